// Round 2
// baseline (8747.471 us; speedup 1.0000x reference)
//
#include <hip/hip_runtime.h>

// Problem constants (fixed by reference):
#define NB    32          // batch
#define CCH   256         // channels
#define HW    1024        // H*W
#define NPIX  (NB*HW)     // 32768 pixels per input
#define DDICT 1024        // dictionary entries

// Output layout (flat fp32 elements, per input section):
//   emb (8388608) | emb_pt (8388608) | idx (32768)  -> section = 16809984
#define EMB_ELEMS  ((size_t)NB*CCH*HW)      // 8388608
#define SEC_ELEMS  (2*EMB_ELEMS + NPIX)     // 16809984

// Stage-1 tiling
#define BK   16
#define TPX  128   // pixels per tile
#define TD   256   // dicts per tile
#define NDT  (DDICT/TD)   // 4 d-tiles

// ---------------- Stage 0: dictionary norms ----------------
__global__ void dict_norms_kernel(const float* __restrict__ dict,
                                  float* __restrict__ norms) {
    int d = blockIdx.x * blockDim.x + threadIdx.x;
    if (d < DDICT) {
        const float4* row = (const float4*)(dict + (size_t)d * CCH);
        float s = 0.f;
#pragma unroll 8
        for (int i = 0; i < CCH / 4; ++i) {
            float4 v = row[i];
            s += v.x * v.x + v.y * v.y + v.z * v.z + v.w * v.w;
        }
        norms[d] = s;
    }
}

// ---------------- Stage 1: tiled GEMM + partial argmin ----------------
// grid: (NPIX/TPX, NDT), block: 256
// Thread (tx,ty): tx = t&15 owns dicts {tx*4 + j*64 + l}, ty = t>>4 owns pixels ty*8+p.
// B reads: B_s[k][tx*4 + j*64] -> lane addresses 16B apart -> conflict-free.
// A reads: 4 unique addresses per wave (broadcast across tx) -> conflict-free.
__global__ __launch_bounds__(256, 2)
void vq_partial_kernel(const float* __restrict__ x,     // [NB][CCH][HW]
                       const float* __restrict__ dict,  // [DDICT][CCH]
                       const float* __restrict__ norms, // [DDICT]
                       float* __restrict__ pdist,       // [NPIX][NDT]
                       int*   __restrict__ pidx) {      // [NPIX][NDT]
    __shared__ float A_s[BK][TPX + 4];   // [k][pixel]
    __shared__ float B_s[BK][TD + 4];    // [k][dict]

    const int t  = threadIdx.x;
    const int tx = t & 15;     // dict group
    const int ty = t >> 4;     // pixel group: 8 pixels

    const int g0  = blockIdx.x * TPX;    // base pixel (global)
    const int d0  = blockIdx.y * TD;     // base dict
    const int n   = g0 / HW;
    const int hw0 = g0 % HW;             // multiple of 128 -> same n for whole tile
    const float* xbase = x + (size_t)n * CCH * HW + hw0;

    float acc[8][16];
#pragma unroll
    for (int p = 0; p < 8; ++p)
#pragma unroll
        for (int j = 0; j < 16; ++j) acc[p][j] = 0.f;

    const int a_l4 = t & 31;   // float4 index within 128-px row
    const int a_row = t >> 5;  // 0..7
    const int b_c4 = t & 3;    // float4 within 16-ch chunk
    const int b_dd = t >> 2;   // 0..63

#pragma unroll 1
    for (int kc = 0; kc < CCH / BK; ++kc) {
        const int c0 = kc * BK;
        // A chunk: A_s[k][p] = x[n][c0+k][hw0+p]
#pragma unroll
        for (int pass = 0; pass < 2; ++pass) {
            int k = pass * 8 + a_row;
            float4 v = *(const float4*)(xbase + (size_t)(c0 + k) * HW + a_l4 * 4);
            *(float4*)&A_s[k][a_l4 * 4] = v;
        }
        // B chunk: B_s[k][dd] = dict[d0+dd][c0+k]
#pragma unroll
        for (int pass = 0; pass < 4; ++pass) {
            int dd = pass * 64 + b_dd;
            float4 v = *(const float4*)(dict + (size_t)(d0 + dd) * CCH + c0 + b_c4 * 4);
            B_s[b_c4 * 4 + 0][dd] = v.x;
            B_s[b_c4 * 4 + 1][dd] = v.y;
            B_s[b_c4 * 4 + 2][dd] = v.z;
            B_s[b_c4 * 4 + 3][dd] = v.w;
        }
        __syncthreads();
#pragma unroll
        for (int k = 0; k < BK; ++k) {
            float4 a0 = *(const float4*)&A_s[k][ty * 8];
            float4 a1 = *(const float4*)&A_s[k][ty * 8 + 4];
            float4 b0 = *(const float4*)&B_s[k][tx * 4];
            float4 b1 = *(const float4*)&B_s[k][tx * 4 + 64];
            float4 b2 = *(const float4*)&B_s[k][tx * 4 + 128];
            float4 b3 = *(const float4*)&B_s[k][tx * 4 + 192];
            float av[8] = {a0.x, a0.y, a0.z, a0.w, a1.x, a1.y, a1.z, a1.w};
            float bv[16] = {b0.x, b0.y, b0.z, b0.w, b1.x, b1.y, b1.z, b1.w,
                            b2.x, b2.y, b2.z, b2.w, b3.x, b3.y, b3.z, b3.w};
#pragma unroll
            for (int p = 0; p < 8; ++p)
#pragma unroll
                for (int j = 0; j < 16; ++j)
                    acc[p][j] = fmaf(av[p], bv[j], acc[p][j]);
        }
        __syncthreads();
    }

    // Epilogue: dist = norm - 2*dot; per-thread argmin over its 16 dicts
    // (local index ascending within thread -> strict < keeps lowest index),
    // then shuffle-reduce across the 16-lane tx group with explicit idx tie-break.
    float nrm[16];
#pragma unroll
    for (int j = 0; j < 4; ++j)
#pragma unroll
        for (int l = 0; l < 4; ++l)
            nrm[j * 4 + l] = norms[d0 + tx * 4 + j * 64 + l];

#pragma unroll 1
    for (int p = 0; p < 8; ++p) {
        float bd = 3.0e38f;
        int   bi = 0;
#pragma unroll
        for (int j = 0; j < 4; ++j)
#pragma unroll
            for (int l = 0; l < 4; ++l) {
                float dist = fmaf(-2.f, acc[p][j * 4 + l], nrm[j * 4 + l]);
                int li = tx * 4 + j * 64 + l;
                if (dist < bd) { bd = dist; bi = li; }
            }
#pragma unroll
        for (int off = 1; off < 16; off <<= 1) {
            float od = __shfl_xor(bd, off);
            int   oi = __shfl_xor(bi, off);
            if (od < bd || (od == bd && oi < bi)) { bd = od; bi = oi; }
        }
        if (tx == 0) {
            int g = g0 + ty * 8 + p;
            pdist[(size_t)g * NDT + blockIdx.y] = bd;
            pidx [(size_t)g * NDT + blockIdx.y] = d0 + bi;
        }
    }
}

// ---------------- Stage 2: final argmin + gather + writes ----------------
// grid: NPIX/64, block: 256 (64 pixels per block; 4 px x 16 ch per thread iter)
__global__ void vq_finalize_kernel(const float* __restrict__ pdist,
                                   const int*   __restrict__ pidx,
                                   const float* __restrict__ dict,
                                   float* __restrict__ out_emb,
                                   float* __restrict__ out_emb_pt,
                                   float* __restrict__ out_idx) {
    __shared__ int idx_s[64];
    const int t  = threadIdx.x;
    const int g0 = blockIdx.x * 64;

    if (t < 64) {
        int g = g0 + t;
        float4 pd = *(const float4*)(pdist + (size_t)g * NDT);
        int4   pi = *(const int4*)  (pidx  + (size_t)g * NDT);
        float best = pd.x; int bi = pi.x;          // ascending tile order:
        if (pd.y < best) { best = pd.y; bi = pi.y; } // strict < keeps lowest idx
        if (pd.z < best) { best = pd.z; bi = pi.z; }
        if (pd.w < best) { best = pd.w; bi = pi.w; }
        idx_s[t] = bi;
        out_idx[g] = (float)bi;
    }
    __syncthreads();

    const int p4 = t & 15;    // 4-pixel group
    const int cg = t >> 4;    // 16 channel groups of 16 channels
    const int n  = g0 / HW;
    const int hw = (g0 % HW) + p4 * 4;
    const float* r0 = dict + (size_t)idx_s[p4 * 4 + 0] * CCH;
    const float* r1 = dict + (size_t)idx_s[p4 * 4 + 1] * CCH;
    const float* r2 = dict + (size_t)idx_s[p4 * 4 + 2] * CCH;
    const float* r3 = dict + (size_t)idx_s[p4 * 4 + 3] * CCH;
    const size_t obase = (size_t)n * CCH * HW + hw;

#pragma unroll 4
    for (int cc = 0; cc < 16; ++cc) {
        int c = cg * 16 + cc;
        float4 v = make_float4(r0[c], r1[c], r2[c], r3[c]);
        size_t o = obase + (size_t)c * HW;
        *(float4*)(out_emb + o)    = v;
        *(float4*)(out_emb_pt + o) = v;
    }
}

extern "C" void kernel_launch(void* const* d_in, const int* in_sizes, int n_in,
                              void* d_out, int out_size, void* d_ws, size_t ws_size,
                              hipStream_t stream) {
    const float* x0   = (const float*)d_in[0];
    const float* x1   = (const float*)d_in[1];
    const float* dict = (const float*)d_in[2];
    float* out = (float*)d_out;

    // Workspace: norms (1024 f) | pdistA | pidxA | pdistB | pidxB  (each NPIX*NDT)
    float* norms  = (float*)d_ws;
    float* pdistA = norms + DDICT;
    int*   pidxA  = (int*)(pdistA + (size_t)NPIX * NDT);
    float* pdistB = (float*)(pidxA + (size_t)NPIX * NDT);
    int*   pidxB  = (int*)(pdistB + (size_t)NPIX * NDT);

    dict_norms_kernel<<<dim3(DDICT / 256), dim3(256), 0, stream>>>(dict, norms);

    dim3 g1(NPIX / TPX, NDT);
    vq_partial_kernel<<<g1, dim3(256), 0, stream>>>(x0, dict, norms, pdistA, pidxA);
    vq_partial_kernel<<<g1, dim3(256), 0, stream>>>(x1, dict, norms, pdistB, pidxB);

    dim3 g2(NPIX / 64);
    vq_finalize_kernel<<<g2, dim3(256), 0, stream>>>(pdistA, pidxA, dict,
                                                     out,
                                                     out + EMB_ELEMS,
                                                     out + 2 * EMB_ELEMS);
    vq_finalize_kernel<<<g2, dim3(256), 0, stream>>>(pdistB, pidxB, dict,
                                                     out + SEC_ELEMS,
                                                     out + SEC_ELEMS + EMB_ELEMS,
                                                     out + SEC_ELEMS + 2 * EMB_ELEMS);
}

// Round 3
// 619.221 us; speedup vs baseline: 14.1266x; 14.1266x over previous
//
#include <hip/hip_runtime.h>

// Problem constants (fixed by reference):
#define NB    32          // batch
#define CCH   256         // channels
#define HW    1024        // H*W
#define NPIX  (NB*HW)     // 32768 pixels per input
#define DDICT 1024        // dictionary entries

// Output layout (flat fp32 elements, per input section):
//   emb (8388608) | emb_pt (8388608) | idx (32768)  -> section = 16809984
#define EMB_ELEMS  ((size_t)NB*CCH*HW)      // 8388608
#define SEC_ELEMS  (2*EMB_ELEMS + NPIX)     // 16809984

// Stage-1 tiling
#define BK   16
#define TPX  128   // pixels per tile
#define TD   256   // dicts per tile
#define NDT  (DDICT/TD)   // 4 d-tiles

// ---------------- Stage 0: dictionary norms ----------------
__global__ void dict_norms_kernel(const float* __restrict__ dict,
                                  float* __restrict__ norms) {
    int d = blockIdx.x * blockDim.x + threadIdx.x;
    if (d < DDICT) {
        const float4* row = (const float4*)(dict + (size_t)d * CCH);
        float s = 0.f;
#pragma unroll 8
        for (int i = 0; i < CCH / 4; ++i) {
            float4 v = row[i];
            s += v.x * v.x + v.y * v.y + v.z * v.z + v.w * v.w;
        }
        norms[d] = s;
    }
}

// ---------------- Stage 1: tiled GEMM + partial argmin ----------------
// grid: (NPIX/TPX, NDT), block: 256
// Thread (tx,ty): tx = t&15 owns dicts {tx*4 + j*64 + l}, ty = t>>4 owns pixels ty*8+p.
// B reads: B_s[k][tx*4 + j*64] -> lane addresses 16B apart -> conflict-free.
// A reads: 4 unique addresses per wave (broadcast across tx) -> conflict-free.
// NOTE: every loop touching acc[][] MUST be fully unrolled — a runtime index
// into acc demotes the whole accumulator to scratch (round-2 regression:
// 30.5 GB WRITE_SIZE, 87% HBM, 9x slowdown).
__global__ __launch_bounds__(256, 2)
void vq_partial_kernel(const float* __restrict__ x,     // [NB][CCH][HW]
                       const float* __restrict__ dict,  // [DDICT][CCH]
                       const float* __restrict__ norms, // [DDICT]
                       float* __restrict__ pdist,       // [NPIX][NDT]
                       int*   __restrict__ pidx) {      // [NPIX][NDT]
    __shared__ float A_s[BK][TPX + 4];   // [k][pixel]
    __shared__ float B_s[BK][TD + 4];    // [k][dict]

    const int t  = threadIdx.x;
    const int tx = t & 15;     // dict group
    const int ty = t >> 4;     // pixel group: 8 pixels

    const int g0  = blockIdx.x * TPX;    // base pixel (global)
    const int d0  = blockIdx.y * TD;     // base dict
    const int n   = g0 / HW;
    const int hw0 = g0 % HW;             // multiple of 128 -> same n for whole tile
    const float* xbase = x + (size_t)n * CCH * HW + hw0;

    float acc[8][16];
#pragma unroll
    for (int p = 0; p < 8; ++p)
#pragma unroll
        for (int j = 0; j < 16; ++j) acc[p][j] = 0.f;

    const int a_l4 = t & 31;   // float4 index within 128-px row
    const int a_row = t >> 5;  // 0..7
    const int b_c4 = t & 3;    // float4 within 16-ch chunk
    const int b_dd = t >> 2;   // 0..63

#pragma unroll 1
    for (int kc = 0; kc < CCH / BK; ++kc) {
        const int c0 = kc * BK;
        // A chunk: A_s[k][p] = x[n][c0+k][hw0+p]
#pragma unroll
        for (int pass = 0; pass < 2; ++pass) {
            int k = pass * 8 + a_row;
            float4 v = *(const float4*)(xbase + (size_t)(c0 + k) * HW + a_l4 * 4);
            *(float4*)&A_s[k][a_l4 * 4] = v;
        }
        // B chunk: B_s[k][dd] = dict[d0+dd][c0+k]
#pragma unroll
        for (int pass = 0; pass < 4; ++pass) {
            int dd = pass * 64 + b_dd;
            float4 v = *(const float4*)(dict + (size_t)(d0 + dd) * CCH + c0 + b_c4 * 4);
            B_s[b_c4 * 4 + 0][dd] = v.x;
            B_s[b_c4 * 4 + 1][dd] = v.y;
            B_s[b_c4 * 4 + 2][dd] = v.z;
            B_s[b_c4 * 4 + 3][dd] = v.w;
        }
        __syncthreads();
#pragma unroll
        for (int k = 0; k < BK; ++k) {
            float4 a0 = *(const float4*)&A_s[k][ty * 8];
            float4 a1 = *(const float4*)&A_s[k][ty * 8 + 4];
            float4 b0 = *(const float4*)&B_s[k][tx * 4];
            float4 b1 = *(const float4*)&B_s[k][tx * 4 + 64];
            float4 b2 = *(const float4*)&B_s[k][tx * 4 + 128];
            float4 b3 = *(const float4*)&B_s[k][tx * 4 + 192];
            float av[8] = {a0.x, a0.y, a0.z, a0.w, a1.x, a1.y, a1.z, a1.w};
            float bv[16] = {b0.x, b0.y, b0.z, b0.w, b1.x, b1.y, b1.z, b1.w,
                            b2.x, b2.y, b2.z, b2.w, b3.x, b3.y, b3.z, b3.w};
#pragma unroll
            for (int p = 0; p < 8; ++p)
#pragma unroll
                for (int j = 0; j < 16; ++j)
                    acc[p][j] = fmaf(av[p], bv[j], acc[p][j]);
        }
        __syncthreads();
    }

    // Epilogue: dist = norm - 2*dot; per-thread argmin over its 16 dicts
    // (local index ascending within thread -> strict < keeps lowest index),
    // then shuffle-reduce across the 16-lane tx group with explicit idx tie-break.
    float nrm[16];
#pragma unroll
    for (int j = 0; j < 4; ++j)
#pragma unroll
        for (int l = 0; l < 4; ++l)
            nrm[j * 4 + l] = norms[d0 + tx * 4 + j * 64 + l];

#pragma unroll
    for (int p = 0; p < 8; ++p) {
        float bd = 3.0e38f;
        int   bi = 0;
#pragma unroll
        for (int j = 0; j < 4; ++j)
#pragma unroll
            for (int l = 0; l < 4; ++l) {
                float dist = fmaf(-2.f, acc[p][j * 4 + l], nrm[j * 4 + l]);
                int li = tx * 4 + j * 64 + l;
                if (dist < bd) { bd = dist; bi = li; }
            }
#pragma unroll
        for (int off = 1; off < 16; off <<= 1) {
            float od = __shfl_xor(bd, off);
            int   oi = __shfl_xor(bi, off);
            if (od < bd || (od == bd && oi < bi)) { bd = od; bi = oi; }
        }
        if (tx == 0) {
            int g = g0 + ty * 8 + p;
            pdist[(size_t)g * NDT + blockIdx.y] = bd;
            pidx [(size_t)g * NDT + blockIdx.y] = d0 + bi;
        }
    }
}

// ---------------- Stage 2: final argmin + gather + writes ----------------
// grid: NPIX/64, block: 256 (64 pixels per block; 4 px x 16 ch per thread iter)
__global__ void vq_finalize_kernel(const float* __restrict__ pdist,
                                   const int*   __restrict__ pidx,
                                   const float* __restrict__ dict,
                                   float* __restrict__ out_emb,
                                   float* __restrict__ out_emb_pt,
                                   float* __restrict__ out_idx) {
    __shared__ int idx_s[64];
    const int t  = threadIdx.x;
    const int g0 = blockIdx.x * 64;

    if (t < 64) {
        int g = g0 + t;
        float4 pd = *(const float4*)(pdist + (size_t)g * NDT);
        int4   pi = *(const int4*)  (pidx  + (size_t)g * NDT);
        float best = pd.x; int bi = pi.x;          // ascending tile order:
        if (pd.y < best) { best = pd.y; bi = pi.y; } // strict < keeps lowest idx
        if (pd.z < best) { best = pd.z; bi = pi.z; }
        if (pd.w < best) { best = pd.w; bi = pi.w; }
        idx_s[t] = bi;
        out_idx[g] = (float)bi;
    }
    __syncthreads();

    const int p4 = t & 15;    // 4-pixel group
    const int cg = t >> 4;    // 16 channel groups of 16 channels
    const int n  = g0 / HW;
    const int hw = (g0 % HW) + p4 * 4;
    const float* r0 = dict + (size_t)idx_s[p4 * 4 + 0] * CCH;
    const float* r1 = dict + (size_t)idx_s[p4 * 4 + 1] * CCH;
    const float* r2 = dict + (size_t)idx_s[p4 * 4 + 2] * CCH;
    const float* r3 = dict + (size_t)idx_s[p4 * 4 + 3] * CCH;
    const size_t obase = (size_t)n * CCH * HW + hw;

#pragma unroll 4
    for (int cc = 0; cc < 16; ++cc) {
        int c = cg * 16 + cc;
        float4 v = make_float4(r0[c], r1[c], r2[c], r3[c]);
        size_t o = obase + (size_t)c * HW;
        *(float4*)(out_emb + o)    = v;
        *(float4*)(out_emb_pt + o) = v;
    }
}

extern "C" void kernel_launch(void* const* d_in, const int* in_sizes, int n_in,
                              void* d_out, int out_size, void* d_ws, size_t ws_size,
                              hipStream_t stream) {
    const float* x0   = (const float*)d_in[0];
    const float* x1   = (const float*)d_in[1];
    const float* dict = (const float*)d_in[2];
    float* out = (float*)d_out;

    // Workspace: norms (1024 f) | pdistA | pidxA | pdistB | pidxB  (each NPIX*NDT)
    float* norms  = (float*)d_ws;
    float* pdistA = norms + DDICT;
    int*   pidxA  = (int*)(pdistA + (size_t)NPIX * NDT);
    float* pdistB = (float*)(pidxA + (size_t)NPIX * NDT);
    int*   pidxB  = (int*)(pdistB + (size_t)NPIX * NDT);

    dict_norms_kernel<<<dim3(DDICT / 256), dim3(256), 0, stream>>>(dict, norms);

    dim3 g1(NPIX / TPX, NDT);
    vq_partial_kernel<<<g1, dim3(256), 0, stream>>>(x0, dict, norms, pdistA, pidxA);
    vq_partial_kernel<<<g1, dim3(256), 0, stream>>>(x1, dict, norms, pdistB, pidxB);

    dim3 g2(NPIX / 64);
    vq_finalize_kernel<<<g2, dim3(256), 0, stream>>>(pdistA, pidxA, dict,
                                                     out,
                                                     out + EMB_ELEMS,
                                                     out + 2 * EMB_ELEMS);
    vq_finalize_kernel<<<g2, dim3(256), 0, stream>>>(pdistB, pidxB, dict,
                                                     out + SEC_ELEMS,
                                                     out + SEC_ELEMS + EMB_ELEMS,
                                                     out + SEC_ELEMS + 2 * EMB_ELEMS);
}

// Round 6
// 530.355 us; speedup vs baseline: 16.4936x; 1.1676x over previous
//
#include <hip/hip_runtime.h>

// Problem constants (fixed by reference):
#define NB    32
#define CCH   256
#define HW    1024
#define NPIX  (NB*HW)     // 32768 pixels per input
#define DDICT 1024

#define EMB_ELEMS  ((size_t)NB*CCH*HW)      // 8388608
#define SEC_ELEMS  (2*EMB_ELEMS + NPIX)     // 16809984

// MFMA GEMM tiling
#define TPX  128           // pixels per block
#define TD   128           // dicts per block
#define NDT  (DDICT/TD)    // 8 d-tiles
#define BK   32            // K per chunk (one 16x16x32 MFMA)
#define NKC  (CCH/BK)      // 8 chunks

#define TAU  0.125f        // near-tie threshold (>> any MFMA/fp32 noise ~1e-3)

typedef __attribute__((ext_vector_type(8))) short bf16x8;   // 8 bf16 = 4 VGPR
typedef __attribute__((ext_vector_type(4))) float f32x4;

// RNE round to bf16; returns bf16 bits, rest = exact residual.
__device__ inline ushort split_rne(float f, float& rest) {
    uint u = __float_as_uint(f);
    uint r = u + 0x7FFFu + ((u >> 16) & 1u);
    rest = f - __uint_as_float(r & 0xFFFF0000u);
    return (ushort)(r >> 16);
}

// ---------------- Stage 0a: dictionary norms (+ zero rescue counters) --------
// UNCHANGED arithmetic vs round 1/3 — rescue kernel depends on bit-identical norms.
__global__ void dict_norms_kernel(const float* __restrict__ dict,
                                  float* __restrict__ norms,
                                  int* __restrict__ cnts) {
    if (blockIdx.x == 0 && threadIdx.x < 2) cnts[threadIdx.x] = 0;
    int d = blockIdx.x * blockDim.x + threadIdx.x;
    if (d < DDICT) {
        const float4* row = (const float4*)(dict + (size_t)d * CCH);
        float s = 0.f;
#pragma unroll 8
        for (int i = 0; i < CCH / 4; ++i) {
            float4 v = row[i];
            s += v.x * v.x + v.y * v.y + v.z * v.z + v.w * v.w;
        }
        norms[d] = s;
    }
}

// ---------------- Stage 0b: 3-way bf16 split of dictionary ----------------
__global__ void dict_split_kernel(const float* __restrict__ dict,
                                  ushort* __restrict__ dH,
                                  ushort* __restrict__ dM,
                                  ushort* __restrict__ dL) {
    int d = blockIdx.x;
    int lane = threadIdx.x;   // 0..63
    float4 f = ((const float4*)(dict + (size_t)d * CCH))[lane];
    float v[4] = {f.x, f.y, f.z, f.w};
    ushort h[4], m[4], l[4];
#pragma unroll
    for (int i = 0; i < 4; ++i) {
        float r1, r2;
        h[i] = split_rne(v[i], r1);
        m[i] = split_rne(r1, r2);
        l[i] = (ushort)(__float_as_uint(r2) >> 16);   // trunc; residual ~2^-26
    }
    size_t o = (size_t)d * CCH + lane * 4;
    *(ushort4*)(dH + o) = make_ushort4(h[0], h[1], h[2], h[3]);
    *(ushort4*)(dM + o) = make_ushort4(m[0], m[1], m[2], m[3]);
    *(ushort4*)(dL + o) = make_ushort4(l[0], l[1], l[2], l[3]);
}

// ---------------- Stage 1: split-bf16 MFMA GEMM + partial top-2 argmin -------
// grid (NDT, NPIX/TPX), block 256 = 4 waves; wave wv owns pixels [wv*32,+32) x
// ALL 128 dicts (disjoint pixels per wave -> no cross-wave race; round-5 fix).
// Tracks (best, idx, second) per pixel per tile — second feeds near-tie rescue.
// NOTE: all acc/frag indices compile-time (round-2 scratch-spill lesson).
__global__ __launch_bounds__(256, 2)
void vq_mfma_kernel(const float* __restrict__ x,     // [NB][CCH][HW]
                    const ushort* __restrict__ dH,
                    const ushort* __restrict__ dM,
                    const ushort* __restrict__ dL,
                    const float* __restrict__ norms,
                    float* __restrict__ pdist,       // [NPIX][NDT] best
                    int*   __restrict__ pidx,        // [NPIX][NDT] best idx
                    float* __restrict__ psec) {      // [NPIX][NDT] second-best
    __shared__ ushort Bs[3][TD * BK];   // [plane][dd*32 + slot*8]  3 x 8 KB

    const int t    = threadIdx.x;
    const int lane = t & 63;
    const int wv   = t >> 6;
    const int lx   = lane & 15;      // MFMA row/col index
    const int q    = lane >> 4;      // k-octet / C-row quad
    const int m0w  = wv * 32;        // wave pixel offset (disjoint strips)

    const int d0  = blockIdx.x * TD;
    const int g0  = blockIdx.y * TPX;
    const int n   = g0 / HW;
    const int hw0 = g0 % HW;         // tile stays within one n (128 | 1024)
    const float* xbase = x + (size_t)n * CCH * HW + hw0 + m0w + lx;

    f32x4 acc[2][8] = {};            // [mi][ni], 64 VGPR

    for (int kc = 0; kc < NKC; ++kc) {
        const int c0 = kc * BK;

        // ---- A: global gather, k-contiguous per lane (A[m=lx][k=q*8+j])
        float a_f[2][8];
#pragma unroll
        for (int mi = 0; mi < 2; ++mi)
#pragma unroll
            for (int j = 0; j < 8; ++j)
                a_f[mi][j] = xbase[(c0 + q * 8 + j) * HW + mi * 16];

        __syncthreads();   // previous chunk's Bs frag reads complete

        // ---- B staging: bf16 planes -> LDS, swizzled (plane index compile-time)
#pragma unroll
        for (int plane = 0; plane < 3; ++plane) {
            const ushort* dp = (plane == 0) ? dH : ((plane == 1) ? dM : dL);
#pragma unroll
            for (int half = 0; half < 2; ++half) {
                int id  = half * 256 + t;
                int dd  = id >> 2, oct = id & 3;
                uint4 v = *(const uint4*)(dp + (size_t)(d0 + dd) * CCH + c0 + oct * 8);
                int slot = (oct + (dd >> 1)) & 3;
                *(uint4*)&Bs[plane][dd * 32 + slot * 8] = v;
            }
        }

        // ---- A: exact 3-way split in registers while B writes drain
        bf16x8 Ah[2], Am[2], Al[2];
#pragma unroll
        for (int mi = 0; mi < 2; ++mi)
#pragma unroll
            for (int j = 0; j < 8; ++j) {
                float r1, r2;
                ushort h = split_rne(a_f[mi][j], r1);
                ushort m = split_rne(r1, r2);
                ushort l = (ushort)(__float_as_uint(r2) >> 16);
                Ah[mi][j] = (short)h; Am[mi][j] = (short)m; Al[mi][j] = (short)l;
            }

        __syncthreads();

        // ---- MFMA: 6 exact-split products (upper triangle), fp32 accumulate
#pragma unroll
        for (int ni = 0; ni < 8; ++ni) {
            int nn   = ni * 16 + lx;
            int slot = (q + (nn >> 1)) & 3;
            int off  = nn * 32 + slot * 8;
            bf16x8 Bh = *(const bf16x8*)&Bs[0][off];
            bf16x8 Bm = *(const bf16x8*)&Bs[1][off];
            bf16x8 Bl = *(const bf16x8*)&Bs[2][off];
#pragma unroll
            for (int mi = 0; mi < 2; ++mi) {
                f32x4 c = acc[mi][ni];
                c = __builtin_amdgcn_mfma_f32_16x16x32_bf16(Ah[mi], Bh, c, 0, 0, 0);
                c = __builtin_amdgcn_mfma_f32_16x16x32_bf16(Ah[mi], Bm, c, 0, 0, 0);
                c = __builtin_amdgcn_mfma_f32_16x16x32_bf16(Am[mi], Bh, c, 0, 0, 0);
                c = __builtin_amdgcn_mfma_f32_16x16x32_bf16(Ah[mi], Bl, c, 0, 0, 0);
                c = __builtin_amdgcn_mfma_f32_16x16x32_bf16(Am[mi], Bm, c, 0, 0, 0);
                c = __builtin_amdgcn_mfma_f32_16x16x32_bf16(Al[mi], Bh, c, 0, 0, 0);
                acc[mi][ni] = c;
            }
        }
    }

    // ---- Epilogue: dist = norm - 2*dot; per-pixel top-2 (b1, i1, b2).
    float nrm[8];
#pragma unroll
    for (int ni = 0; ni < 8; ++ni) nrm[ni] = norms[d0 + ni * 16 + lx];

#pragma unroll
    for (int mi = 0; mi < 2; ++mi)
#pragma unroll
        for (int r = 0; r < 4; ++r) {
            float b1 = 3.0e38f, b2 = 3.0e38f; int i1 = 0;
#pragma unroll
            for (int ni = 0; ni < 8; ++ni) {        // ascending dict within lane
                float dist = fmaf(-2.f, acc[mi][ni][r], nrm[ni]);
                if (dist < b1)      { b2 = b1; b1 = dist; i1 = ni * 16 + lx; }
                else if (dist < b2) { b2 = dist; }
            }
#pragma unroll
            for (int off = 1; off < 16; off <<= 1) { // 16-lane group, idx tie-break
                float o1 = __shfl_xor(b1, off);
                int   oi = __shfl_xor(i1, off);
                float o2 = __shfl_xor(b2, off);
                if (o1 < b1 || (o1 == b1 && oi < i1)) {
                    b2 = fminf(b1, o2); b1 = o1; i1 = oi;
                } else {
                    b2 = fminf(b2, o1);
                }
            }
            if (lx == 0) {
                int g = g0 + m0w + mi * 16 + q * 4 + r;   // C-row = quad*4 + reg
                pdist[(size_t)g * NDT + blockIdx.x] = b1;
                pidx [(size_t)g * NDT + blockIdx.x] = d0 + i1;
                psec [(size_t)g * NDT + blockIdx.x] = b2;
            }
        }
}

// ---------------- Stage 2: final top-2 merge + flag + gather + writes --------
__global__ void vq_finalize_kernel(const float* __restrict__ pdist,
                                   const int*   __restrict__ pidx,
                                   const float* __restrict__ psec,
                                   const float* __restrict__ dict,
                                   float* __restrict__ out_emb,
                                   float* __restrict__ out_emb_pt,
                                   float* __restrict__ out_idx,
                                   int* __restrict__ cnt,
                                   int* __restrict__ list) {
    __shared__ int idx_s[64];
    const int t  = threadIdx.x;
    const int g0 = blockIdx.x * 64;

    if (t < 64) {
        int g = g0 + t;
        float pd_[8]; int pi_[8]; float ps_[8];
        *(float4*)&pd_[0] = *(const float4*)(pdist + (size_t)g * NDT);
        *(float4*)&pd_[4] = *(const float4*)(pdist + (size_t)g * NDT + 4);
        *(int4*)  &pi_[0] = *(const int4*)  (pidx  + (size_t)g * NDT);
        *(int4*)  &pi_[4] = *(const int4*)  (pidx  + (size_t)g * NDT + 4);
        *(float4*)&ps_[0] = *(const float4*)(psec  + (size_t)g * NDT);
        *(float4*)&ps_[4] = *(const float4*)(psec  + (size_t)g * NDT + 4);
        float b1 = pd_[0]; int i1 = pi_[0]; float b2 = ps_[0];
#pragma unroll
        for (int qk = 1; qk < 8; ++qk) {   // ascending tile: lowest idx on ties
            float c1 = pd_[qk], c2 = ps_[qk]; int ci = pi_[qk];
            if (c1 < b1) { b2 = fminf(b1, c2); b1 = c1; i1 = ci; }
            else         { b2 = fminf(b2, c1); }
        }
        idx_s[t] = i1;
        out_idx[g] = (float)i1;
        if (b2 - b1 < TAU) {               // near-tie: exact-fp32 rescue later
            int slot = atomicAdd(cnt, 1);
            list[slot] = g;
        }
    }
    __syncthreads();

    const int p4 = t & 15;    // 4-pixel group
    const int cg = t >> 4;    // 16 channel-groups of 16 channels
    const int nb = g0 / HW;
    const int hw = (g0 % HW) + p4 * 4;
    const float* r0 = dict + (size_t)idx_s[p4 * 4 + 0] * CCH;
    const float* r1 = dict + (size_t)idx_s[p4 * 4 + 1] * CCH;
    const float* r2 = dict + (size_t)idx_s[p4 * 4 + 2] * CCH;
    const float* r3 = dict + (size_t)idx_s[p4 * 4 + 3] * CCH;
    const size_t obase = (size_t)nb * CCH * HW + hw;

#pragma unroll
    for (int cq = 0; cq < 4; ++cq) {
        int c = cg * 16 + cq * 4;
        float4 q0 = *(const float4*)(r0 + c);
        float4 q1 = *(const float4*)(r1 + c);
        float4 q2 = *(const float4*)(r2 + c);
        float4 q3 = *(const float4*)(r3 + c);
        float4 v0 = make_float4(q0.x, q1.x, q2.x, q3.x);
        float4 v1 = make_float4(q0.y, q1.y, q2.y, q3.y);
        float4 v2 = make_float4(q0.z, q1.z, q2.z, q3.z);
        float4 v3 = make_float4(q0.w, q1.w, q2.w, q3.w);
        *(float4*)(out_emb    + obase + (size_t)(c + 0) * HW) = v0;
        *(float4*)(out_emb_pt + obase + (size_t)(c + 0) * HW) = v0;
        *(float4*)(out_emb    + obase + (size_t)(c + 1) * HW) = v1;
        *(float4*)(out_emb_pt + obase + (size_t)(c + 1) * HW) = v1;
        *(float4*)(out_emb    + obase + (size_t)(c + 2) * HW) = v2;
        *(float4*)(out_emb_pt + obase + (size_t)(c + 2) * HW) = v2;
        *(float4*)(out_emb    + obase + (size_t)(c + 3) * HW) = v3;
        *(float4*)(out_emb_pt + obase + (size_t)(c + 3) * HW) = v3;
    }
}

// ---------------- Stage 3: exact-fp32 rescue of near-tie pixels --------------
// Static grid, device-side count (graph-capture safe). Recomputes flagged
// pixels vs ALL 1024 dicts with bit-identical round-3 arithmetic (fmaf chain,
// k ascending; dist = fmaf(-2,dot,norm); lexicographic (dist,idx) argmin),
// then overwrites idx + both embedded rows.
__global__ __launch_bounds__(256)
void vq_rescue_kernel(const float* __restrict__ x,
                      const float* __restrict__ dict,
                      const float* __restrict__ norms,
                      const int* __restrict__ cnt,
                      const int* __restrict__ list,
                      float* __restrict__ out_emb,
                      float* __restrict__ out_emb_pt,
                      float* __restrict__ out_idx) {
    __shared__ float xr[CCH];
    __shared__ float rd_s[4];
    __shared__ int   ri_s[4];
    __shared__ int   bi_s;
    const int t    = threadIdx.x;
    const int lane = t & 63;
    const int wv   = t >> 6;
    const int total = *cnt;

    for (int w = blockIdx.x; w < total; w += gridDim.x) {
        const int g  = list[w];
        const int n  = g / HW;
        const int hw = g % HW;
        xr[t] = x[(size_t)n * CCH * HW + (size_t)t * HW + hw];
        __syncthreads();

        float bd = 3.0e38f; int bi = 0;
#pragma unroll
        for (int dd = 0; dd < 4; ++dd) {          // dicts {t, 256+t, 512+t, 768+t}
            int d = dd * 256 + t;                 // ascending within thread
            const float* drow = dict + (size_t)d * CCH;
            float dot = 0.f;
#pragma unroll 8
            for (int k = 0; k < CCH; ++k) dot = fmaf(xr[k], drow[k], dot);
            float dist = fmaf(-2.f, dot, norms[d]);
            if (dist < bd) { bd = dist; bi = d; }
        }
#pragma unroll
        for (int off = 1; off < 64; off <<= 1) {  // wave lexicographic min
            float od = __shfl_xor(bd, off);
            int   oi = __shfl_xor(bi, off);
            if (od < bd || (od == bd && oi < bi)) { bd = od; bi = oi; }
        }
        if (lane == 0) { rd_s[wv] = bd; ri_s[wv] = bi; }
        __syncthreads();
        if (t == 0) {
            float fb = rd_s[0]; int fi = ri_s[0];
#pragma unroll
            for (int q2 = 1; q2 < 4; ++q2)
                if (rd_s[q2] < fb || (rd_s[q2] == fb && ri_s[q2] < fi)) {
                    fb = rd_s[q2]; fi = ri_s[q2];
                }
            bi_s = fi;
            out_idx[g] = (float)fi;
        }
        __syncthreads();
        float v = dict[(size_t)bi_s * CCH + t];
        size_t o = (size_t)n * CCH * HW + (size_t)t * HW + hw;
        out_emb[o]    = v;
        out_emb_pt[o] = v;
        __syncthreads();   // xr reused next iteration
    }
}

extern "C" void kernel_launch(void* const* d_in, const int* in_sizes, int n_in,
                              void* d_out, int out_size, void* d_ws, size_t ws_size,
                              hipStream_t stream) {
    const float* x0   = (const float*)d_in[0];
    const float* x1   = (const float*)d_in[1];
    const float* dict = (const float*)d_in[2];
    float* out = (float*)d_out;

    // ws layout (bytes): norms 4K | dH/dM/dL 3x512K | pdistA/pidxA/psecA 3x1M |
    //                    pdistB/pidxB/psecB 3x1M | listA 128K | listB 128K | cnts 8
    float*  norms  = (float*)d_ws;
    ushort* dH     = (ushort*)(norms + DDICT);
    ushort* dM     = dH + (size_t)DDICT * CCH;
    ushort* dL     = dM + (size_t)DDICT * CCH;
    float*  pdistA = (float*)(dL + (size_t)DDICT * CCH);
    int*    pidxA  = (int*)(pdistA + (size_t)NPIX * NDT);
    float*  psecA  = (float*)(pidxA + (size_t)NPIX * NDT);
    float*  pdistB = psecA + (size_t)NPIX * NDT;
    int*    pidxB  = (int*)(pdistB + (size_t)NPIX * NDT);
    float*  psecB  = (float*)(pidxB + (size_t)NPIX * NDT);
    int*    listA  = (int*)(psecB + (size_t)NPIX * NDT);
    int*    listB  = listA + NPIX;
    int*    cnts   = listB + NPIX;   // cnts[0]=A, cnts[1]=B

    dict_norms_kernel<<<dim3(DDICT / 256), dim3(256), 0, stream>>>(dict, norms, cnts);
    dict_split_kernel<<<dim3(DDICT), dim3(64), 0, stream>>>(dict, dH, dM, dL);

    dim3 g1(NDT, NPIX / TPX);
    vq_mfma_kernel<<<g1, dim3(256), 0, stream>>>(x0, dH, dM, dL, norms,
                                                 pdistA, pidxA, psecA);
    vq_mfma_kernel<<<g1, dim3(256), 0, stream>>>(x1, dH, dM, dL, norms,
                                                 pdistB, pidxB, psecB);

    dim3 g2(NPIX / 64);
    vq_finalize_kernel<<<g2, dim3(256), 0, stream>>>(pdistA, pidxA, psecA, dict,
                                                     out,
                                                     out + EMB_ELEMS,
                                                     out + 2 * EMB_ELEMS,
                                                     cnts + 0, listA);
    vq_finalize_kernel<<<g2, dim3(256), 0, stream>>>(pdistB, pidxB, psecB, dict,
                                                     out + SEC_ELEMS,
                                                     out + SEC_ELEMS + EMB_ELEMS,
                                                     out + SEC_ELEMS + 2 * EMB_ELEMS,
                                                     cnts + 1, listB);

    vq_rescue_kernel<<<dim3(1024), dim3(256), 0, stream>>>(x0, dict, norms,
                                                           cnts + 0, listA,
                                                           out,
                                                           out + EMB_ELEMS,
                                                           out + 2 * EMB_ELEMS);
    vq_rescue_kernel<<<dim3(1024), dim3(256), 0, stream>>>(x1, dict, norms,
                                                           cnts + 1, listB,
                                                           out + SEC_ELEMS,
                                                           out + SEC_ELEMS + EMB_ELEMS,
                                                           out + SEC_ELEMS + 2 * EMB_ELEMS);
}